// Round 4
// baseline (215.624 us; speedup 1.0000x reference)
//
#include <hip/hip_runtime.h>
#include <math.h>

#define L_   8192
#define D_   512
#define E_   8
#define DE_  4096     // D_*E_
#define C_   64       // chunks
#define LC_  128      // output rows per chunk  (C_*LC_ == L_)
#define W_   192      // warmup rows: b_max^192 = sigmoid(pi)^192 ~ 3e-4 -> err ~1.5e-3
#define ST_  16       // software-pipeline stage width (multiple of ST_ divides all trip counts)

typedef float f4_t __attribute__((ext_vector_type(4)));

__device__ __forceinline__ float sigmoidf_(float v) {
    return 1.0f / (1.0f + expf(-v));
}

// Single pass: block (c, sub) replays rows [start, cstart) from zero state
// (or exactly from l=0 with init carry x[0,d] when start==0), then emits rows
// [cstart, cstart+LC_). Each thread owns 4 consecutive e-chains -> f4
// nontemporal stores, 1 KB contiguous per wave. Grid = 256 = 1 block/CU.
__global__ __launch_bounds__(256) void ema_onepass(const float* __restrict__ x,
                                                   const float* __restrict__ ld,
                                                   float* __restrict__ out) {
    const int c   = blockIdx.x >> 2;                        // chunk 0..63
    const int g   = ((blockIdx.x & 3) << 8) + threadIdx.x;  // group 0..1023
    const int d   = g >> 1;
    const int eb  = (g & 1) << 2;

    const int cstart = c * LC_;
    const int start  = (cstart >= W_) ? (cstart - W_) : 0;
    const int nStages  = (cstart + LC_ - start) / ST_;      // 8, 16, or 20
    const int outStage = (cstart - start) / ST_;            // first emitting stage

    float a[4], b[4];
#pragma unroll
    for (int e = 0; e < 4; ++e) { a[e] = sigmoidf_(ld[eb + e]); b[e] = 1.0f - a[e]; }

    f4_t y;
    if (start == 0) {
        const float x0 = x[d];            // carry before step 0 is x[0, d]
        y.x = x0; y.y = x0; y.z = x0; y.w = x0;
    } else {
        y.x = 0.f; y.y = 0.f; y.z = 0.f; y.w = 0.f;
    }

    const float* xp = x + (size_t)start * D_ + d;
    float* op = out + (size_t)cstart * DE_ + 4 * g;

    float xs[2][ST_];
#pragma unroll
    for (int j = 0; j < ST_; ++j) xs[0][j] = xp[(size_t)j * D_];

    for (int st = 0; st < nStages; ++st) {
        if (st + 1 < nStages) {
#pragma unroll
            for (int j = 0; j < ST_; ++j)
                xs[(st + 1) & 1][j] = xp[(size_t)((st + 1) * ST_ + j) * D_];
        }
        const bool emit  = (st >= outStage);                 // wave-uniform
        const int  lbase = start + st * ST_ - cstart;        // row rel. chunk
#pragma unroll
        for (int j = 0; j < ST_; ++j) {
            const float xv = xs[st & 1][j];
            y.x = fmaf(b[0], y.x, a[0] * xv);
            y.y = fmaf(b[1], y.y, a[1] * xv);
            y.z = fmaf(b[2], y.z, a[2] * xv);
            y.w = fmaf(b[3], y.w, a[3] * xv);
            if (emit)
                __builtin_nontemporal_store(y, (f4_t*)(op + (size_t)(lbase + j) * DE_));
        }
    }
}

extern "C" void kernel_launch(void* const* d_in, const int* in_sizes, int n_in,
                              void* d_out, int out_size, void* d_ws, size_t ws_size,
                              hipStream_t stream) {
    const float* x  = (const float*)d_in[0];
    const float* ld = (const float*)d_in[1];
    float* out = (float*)d_out;
    (void)d_ws; (void)ws_size;

    ema_onepass<<<C_ * 4, 256, 0, stream>>>(x, ld, out);
}